// Round 2
// baseline (638.621 us; speedup 1.0000x reference)
//
#include <hip/hip_runtime.h>
#include <hip/hip_bf16.h>

// Problem constants (B=4, N=2048, D_IN=768, H=12, D_HEAD=64)
#define NSEQ 2048
#define DIN  768
#define NH   12

typedef __attribute__((ext_vector_type(8))) short bf16x8;
typedef __attribute__((ext_vector_type(4))) short short4v;
typedef __attribute__((ext_vector_type(4))) float f32x4;

__device__ __forceinline__ unsigned short f2bf(float f) {
    unsigned u = __builtin_bit_cast(unsigned, f);
    u += 0x7FFFu + ((u >> 16) & 1u);   // RNE
    return (unsigned short)(u >> 16);
}

// ---------------- cast kernels ----------------
__global__ __launch_bounds__(256) void cast_x_k(const float* __restrict__ x,
                                                short* __restrict__ xb, int n4) {
    int i = blockIdx.x * 256 + threadIdx.x;
    if (i >= n4) return;
    float4 v = ((const float4*)x)[i];
    short4v o;
    o[0] = (short)f2bf(v.x); o[1] = (short)f2bf(v.y);
    o[2] = (short)f2bf(v.z); o[3] = (short)f2bf(v.w);
    ((short4v*)xb)[i] = o;
}

// WT[c][k], c = m*768 + h*64 + e  (m in {q,k,v}), source W[h][k][e]
__global__ __launch_bounds__(256) void cast_wqkv_k(const float* __restrict__ Wq,
                                                   const float* __restrict__ Wk,
                                                   const float* __restrict__ Wv,
                                                   short* __restrict__ wt) {
    int tid = blockIdx.x * 256 + threadIdx.x;  // 2304*96 threads
    int c = tid / 96;
    int k0 = (tid % 96) * 8;
    int m = c / 768, rem = c - m * 768;
    const float* W = (m == 0) ? Wq : ((m == 1) ? Wk : Wv);
    const float* src = W + (rem >> 6) * (768 * 64) + (rem & 63);
    bf16x8 o;
    #pragma unroll
    for (int j = 0; j < 8; ++j) o[j] = (short)f2bf(src[(k0 + j) * 64]);
    *(bf16x8*)(wt + (size_t)c * 768 + k0) = o;
}

// WoT[c][k] = Wo[k][c]
__global__ __launch_bounds__(256) void cast_wo_k(const float* __restrict__ Wo,
                                                 short* __restrict__ wto) {
    int tid = blockIdx.x * 256 + threadIdx.x;  // 768*96 threads
    int c = tid / 96;
    int k0 = (tid % 96) * 8;
    bf16x8 o;
    #pragma unroll
    for (int j = 0; j < 8; ++j) o[j] = (short)f2bf(Wo[(size_t)(k0 + j) * 768 + c]);
    *(bf16x8*)(wto + (size_t)c * 768 + k0) = o;
}

// ---------------- GEMM: C[M][N] = A[M][768] * Bt[N][768]^T ----------------
// MODE 0: QKV projection epilogue (bias, q*0.125, q/k -> qk buf, v -> vT transposed)
// MODE 1: output projection epilogue (bias, f32 store)
template<int BM, int BN, int MODE>
__global__ __launch_bounds__(256)
void gemm_bf16(const short* __restrict__ A, const short* __restrict__ Bt,
               short* __restrict__ qk, short* __restrict__ vT,
               const float* __restrict__ bq, const float* __restrict__ bk,
               const float* __restrict__ bv,
               float* __restrict__ outf, const float* __restrict__ bo)
{
    constexpr int K = 768;
    constexpr int WM = BM / 32;   // row frags per wave (wave tile BM/2 rows)
    constexpr int WN = BN / 32;   // col frags per wave (wave tile BN/2 cols)
    const int lane = threadIdx.x & 63;
    const int wid  = threadIdx.x >> 6;
    const int l15 = lane & 15, lg = lane >> 4;
    const int wm = wid >> 1, wn = wid & 1;
    const int row0 = blockIdx.x * BM + wm * (BM / 2);
    const int col0 = blockIdx.y * BN + wn * (BN / 2);

    f32x4 acc[WM][WN];
    #pragma unroll
    for (int i = 0; i < WM; ++i)
        #pragma unroll
        for (int j = 0; j < WN; ++j) acc[i][j] = (f32x4){0.f, 0.f, 0.f, 0.f};

    // A frag: row = l15, k = lg*8 + j (contiguous).  B frag: col = l15, same k.
    const short* Ap = A  + (size_t)(row0 + l15) * K + lg * 8;
    const short* Bp = Bt + (size_t)(col0 + l15) * K + lg * 8;

    #pragma unroll 2
    for (int k0 = 0; k0 < K; k0 += 32) {
        bf16x8 a[WM], b[WN];
        #pragma unroll
        for (int i = 0; i < WM; ++i) a[i] = *(const bf16x8*)(Ap + i * 16 * K + k0);
        #pragma unroll
        for (int j = 0; j < WN; ++j) b[j] = *(const bf16x8*)(Bp + j * 16 * K + k0);
        #pragma unroll
        for (int i = 0; i < WM; ++i)
            #pragma unroll
            for (int j = 0; j < WN; ++j)
                acc[i][j] = __builtin_amdgcn_mfma_f32_16x16x32_bf16(a[i], b[j], acc[i][j], 0, 0, 0);
    }

    // C/D layout: col = l15, row = lg*4 + reg  [verified m89/m91]
    if (MODE == 0) {
        #pragma unroll
        for (int i = 0; i < WM; ++i) {
            const int rowb = row0 + i * 16 + lg * 4;
            #pragma unroll
            for (int j = 0; j < WN; ++j) {
                const int col = col0 + j * 16 + l15;
                const int m = col / 768;
                const int rem = col - m * 768;           // h*64 + e
                const float bias = ((m == 0) ? bq : (m == 1) ? bk : bv)[rem];
                if (m < 2) {
                    const float sc = (m == 0) ? 0.125f : 1.0f;  // fold 1/sqrt(64) into q
                    #pragma unroll
                    for (int r = 0; r < 4; ++r) {
                        float v = (acc[i][j][r] + bias) * sc;
                        qk[(size_t)(rowb + r) * 1536 + col] = (short)f2bf(v);
                    }
                } else {
                    // v stored transposed: vT[b*768 + rem][n], 4 consecutive n per lane
                    short4v pk;
                    #pragma unroll
                    for (int r = 0; r < 4; ++r) pk[r] = (short)f2bf(acc[i][j][r] + bias);
                    const int bb = rowb >> 11;      // batch
                    const int n0 = rowb & 2047;     // seq pos
                    *(short4v*)(vT + ((size_t)(bb * 768 + rem)) * 2048 + n0) = pk;
                }
            }
        }
    } else {
        #pragma unroll
        for (int i = 0; i < WM; ++i) {
            const int rowb = row0 + i * 16 + lg * 4;
            #pragma unroll
            for (int j = 0; j < WN; ++j) {
                const int col = col0 + j * 16 + l15;
                const float bias = bo[col];
                #pragma unroll
                for (int r = 0; r < 4; ++r)
                    outf[(size_t)(rowb + r) * 768 + col] = acc[i][j][r] + bias;
            }
        }
    }
}

// ---------------- flash attention ----------------
// grid: (B*H) * (N/64) blocks, 256 thr (4 waves). Each wave owns 16 q-rows,
// iterates KV in tiles of 64. q pre-scaled by 1/8. K/V read direct from
// global (L2-resident). P re-layouts through per-wave LDS.
__global__ __launch_bounds__(256)
void attn_k(const short* __restrict__ qk, const short* __restrict__ vT,
            short* __restrict__ ctx)
{
    __shared__ short Plds[4][16][72];   // per-wave 16x64 P, padded (2-way = free)
    const int lane = threadIdx.x & 63;
    const int wid  = threadIdx.x >> 6;
    const int l15 = lane & 15, lg = lane >> 4;
    const int bid = blockIdx.x;
    const int qb = bid & 31;            // 32 q-chunks of 64
    const int bh = bid >> 5;            // 0..47
    const int b = bh / NH, h = bh - b * NH;
    const int q0 = qb * 64 + wid * 16;  // this wave's q-row base

    const short* qp = qk + (size_t)b * (NSEQ * 1536) + h * 64;   // q[n][e] @ qp[n*1536+e]
    const short* kp = qp + 768;                                   // k[n][e]
    const short* vp = vT + (size_t)(b * 768 + h * 64) * NSEQ;     // vT[e][n] @ vp[e*2048+n]

    bf16x8 qa[2];
    #pragma unroll
    for (int kk = 0; kk < 2; ++kk)
        qa[kk] = *(const bf16x8*)(qp + (size_t)(q0 + l15) * 1536 + kk * 32 + lg * 8);

    f32x4 o[4];
    #pragma unroll
    for (int i = 0; i < 4; ++i) o[i] = (f32x4){0.f, 0.f, 0.f, 0.f};
    float mr[4] = {-1e30f, -1e30f, -1e30f, -1e30f};
    float lr[4] = {0.f, 0.f, 0.f, 0.f};

    #pragma unroll 1
    for (int kv0 = 0; kv0 < NSEQ; kv0 += 64) {
        // K fragments: B-op of S = Q*K^T; lane reads K row (cf*16+l15), e contiguous
        bf16x8 kb[4][2];
        #pragma unroll
        for (int cf = 0; cf < 4; ++cf)
            #pragma unroll
            for (int kk = 0; kk < 2; ++kk)
                kb[cf][kk] = *(const bf16x8*)(kp + (size_t)(kv0 + cf * 16 + l15) * 1536 + kk * 32 + lg * 8);

        f32x4 s[4];
        #pragma unroll
        for (int cf = 0; cf < 4; ++cf) {
            s[cf] = __builtin_amdgcn_mfma_f32_16x16x32_bf16(qa[0], kb[cf][0], (f32x4){0.f,0.f,0.f,0.f}, 0, 0, 0);
            s[cf] = __builtin_amdgcn_mfma_f32_16x16x32_bf16(qa[1], kb[cf][1], s[cf], 0, 0, 0);
        }

        // V fragments (issued early; independent of softmax)
        bf16x8 vb[4][2];
        #pragma unroll
        for (int vc = 0; vc < 4; ++vc)
            #pragma unroll
            for (int kk = 0; kk < 2; ++kk)
                vb[vc][kk] = *(const bf16x8*)(vp + (size_t)(vc * 16 + l15) * NSEQ + kv0 + kk * 32 + lg * 8);

        // online softmax over rows (row = lg*4+r, cols spread over l15 x 4 frags)
        float mn[4], al[4];
        #pragma unroll
        for (int r = 0; r < 4; ++r) {
            float mx = fmaxf(fmaxf(s[0][r], s[1][r]), fmaxf(s[2][r], s[3][r]));
            #pragma unroll
            for (int d = 1; d < 16; d <<= 1) mx = fmaxf(mx, __shfl_xor(mx, d, 64));
            mn[r] = fmaxf(mr[r], mx);
            al[r] = __expf(mr[r] - mn[r]);
            mr[r] = mn[r];
        }
        float p[4][4];
        float rs[4] = {0.f, 0.f, 0.f, 0.f};
        #pragma unroll
        for (int cf = 0; cf < 4; ++cf)
            #pragma unroll
            for (int r = 0; r < 4; ++r) {
                p[cf][r] = __expf(s[cf][r] - mn[r]);
                rs[r] += p[cf][r];
            }
        #pragma unroll
        for (int r = 0; r < 4; ++r) {
            #pragma unroll
            for (int d = 1; d < 16; d <<= 1) rs[r] += __shfl_xor(rs[r], d, 64);
            lr[r] = lr[r] * al[r] + rs[r];
        }
        #pragma unroll
        for (int vc = 0; vc < 4; ++vc)
            #pragma unroll
            for (int r = 0; r < 4; ++r) o[vc][r] *= al[r];

        // P (C/D layout) -> LDS -> A-frag layout. Same-wave, in-order DS pipe.
        #pragma unroll
        for (int cf = 0; cf < 4; ++cf)
            #pragma unroll
            for (int r = 0; r < 4; ++r)
                Plds[wid][lg * 4 + r][cf * 16 + l15] = (short)f2bf(p[cf][r]);

        asm volatile("s_waitcnt lgkmcnt(0)" ::: "memory");
        __builtin_amdgcn_sched_barrier(0);

        bf16x8 pa[2];
        #pragma unroll
        for (int kk = 0; kk < 2; ++kk)
            pa[kk] = *(const bf16x8*)(&Plds[wid][l15][kk * 32 + lg * 8]);
        asm volatile("" ::: "memory");   // pin reads before next iter's writes

        #pragma unroll
        for (int vc = 0; vc < 4; ++vc) {
            o[vc] = __builtin_amdgcn_mfma_f32_16x16x32_bf16(pa[0], vb[vc][0], o[vc], 0, 0, 0);
            o[vc] = __builtin_amdgcn_mfma_f32_16x16x32_bf16(pa[1], vb[vc][1], o[vc], 0, 0, 0);
        }
    }

    #pragma unroll
    for (int vc = 0; vc < 4; ++vc)
        #pragma unroll
        for (int r = 0; r < 4; ++r) {
            float v = o[vc][r] / lr[r];
            ctx[(size_t)(b * NSEQ + q0 + lg * 4 + r) * 768 + h * 64 + vc * 16 + l15] = (short)f2bf(v);
        }
}

// ---------------- launch ----------------
extern "C" void kernel_launch(void* const* d_in, const int* in_sizes, int n_in,
                              void* d_out, int out_size, void* d_ws, size_t ws_size,
                              hipStream_t stream) {
    (void)in_sizes; (void)n_in; (void)out_size; (void)ws_size;
    const float* x  = (const float*)d_in[0];
    const float* Wq = (const float*)d_in[1];
    const float* bq = (const float*)d_in[2];
    const float* Wk = (const float*)d_in[3];
    const float* bk = (const float*)d_in[4];
    const float* Wv = (const float*)d_in[5];
    const float* bv = (const float*)d_in[6];
    const float* Wo = (const float*)d_in[7];
    const float* bo = (const float*)d_in[8];
    float* out = (float*)d_out;

    char* ws = (char*)d_ws;
    short* xb  = (short*)(ws);             // x bf16            12,582,912 B
    short* wt  = (short*)(ws + 12582912);  // WT[2304][768]      3,538,944 B
    short* wto = (short*)(ws + 16121856);  // WoT[768][768]      1,179,648 B
    short* qk  = (short*)(ws + 17301504);  // q|k [8192][1536]  25,165,824 B
    short* vT  = (short*)(ws + 42467328);  // vT[3072][2048]    12,582,912 B
    short* ctx = (short*)(ws + 55050240);  // ctx [8192][768]   12,582,912 B
                                           // total 67,633,152 B

    cast_x_k   <<<6144, 256, 0, stream>>>(x, xb, (4 * NSEQ * DIN) / 4);
    cast_wqkv_k<<< 864, 256, 0, stream>>>(Wq, Wk, Wv, wt);
    cast_wo_k  <<< 288, 256, 0, stream>>>(Wo, wto);

    // QKV projection: M=8192, N=2304, K=768
    gemm_bf16<128, 128, 0><<<dim3(64, 18), 256, 0, stream>>>(
        xb, wt, qk, vT, bq, bk, bv, nullptr, nullptr);

    // attention: 48 (b,h) x 32 q-chunks
    attn_k<<<48 * 32, 256, 0, stream>>>(qk, vT, ctx);

    // output projection: M=8192, N=768, K=768
    gemm_bf16<64, 128, 1><<<dim3(128, 6), 256, 0, stream>>>(
        ctx, wto, nullptr, nullptr, nullptr, nullptr, nullptr, out, bo);
}